// Round 6
// baseline (758.473 us; speedup 1.0000x reference)
//
#include <hip/hip_runtime.h>
#include <hip/hip_fp16.h>
#include <hip/hip_cooperative_groups.h>
#include <math.h>

namespace cg = cooperative_groups;
typedef unsigned long long u64;

#define NN 8192
#define EE 81920
#define E2C 1310720
#define HSZ (1 << 18)
#define HMASK (HSZ - 1)
// mega partition geometry: PB workers x NBIN bins, per-cell capacity CAP (atomic-free)
#define NBIN 160          // dst >> 9 : bins of 512 edge-nodes
#define PB 256            // partition workers, each handles E2C/PB = 5120 entries
#define PCHUNK (E2C / PB)
#define CAP 80            // Poisson(32) tail beyond 80: ~1e-11 per cell
// fallback (round-5) geometry
#define FB_BCAP 9216

__device__ __forceinline__ float wsum(float v) {
#pragma unroll
  for (int m = 32; m > 0; m >>= 1) v += __shfl_xor(v, m, 64);
  return v;
}
__device__ __forceinline__ float lrelu(float x) { return x > 0.f ? x : 0.2f * x; }
__device__ __forceinline__ unsigned packh2(float a, float b) {
  __half2 h = __floats2half2_rn(a, b);
  return *reinterpret_cast<unsigned*>(&h);
}
__device__ __forceinline__ void atomic_pk_add_f16(unsigned* addr, unsigned data) {
  asm volatile("global_atomic_pk_add_f16 %0, %1, off" :: "v"(addr), "v"(data) : "memory");
}
__device__ __forceinline__ int hfind(const int* __restrict__ keys, int key) {
  unsigned i = ((unsigned)key * 2654435761u) >> 14 & HMASK;
  while (true) {
    int k = keys[i];
    if (k == key) return (int)i;
    if (k == -1) return -1;
    i = (i + 1) & HMASK;
  }
}

struct KP {
  const float *x, *embed, *noise, *tmp, *gat_W, *att_s, *att_d, *gat_b, *lin_W, *lin_b;
  const float *W1, *W2, *W3, *Wc;
  const int *row, *col, *src2, *dst2;
  float *out;
  float4 *pN, *qN;
  float2 *asz;
  float *ad;
  int *colCnt, *colOffs, *colCur;
  int *hKeys;
  unsigned *hPair;
  u64 *bucket;
  int *cellCnt;
  float *gvec, *gbScalar;
  float *H1, *H2;
  int2 *csrP;
};

// ============================ MEGA (cooperative) ============================
__global__ __launch_bounds__(256, 2) void mega(KP p) {
  cg::grid_group grid = cg::this_grid();
  __shared__ __align__(16) char smemRaw[74240];  // 72.5 KB: max(Wl+Tl+gpart, phase scratch)
  float* sm = (float*)smemRaw;
  const int t = threadIdx.x, bid = blockIdx.x, nb = gridDim.x;
  const int lane = t & 63, wv = t >> 6;

  // ---- P0: init + per-block combo(LDS) + nodescal + gbScalar ----
  for (int i = bid * 256 + t; i < HSZ; i += nb * 256) { p.hKeys[i] = -1; p.hPair[i] = 0u; }
  for (int i = bid * 256 + t; i < NN; i += nb * 256) p.colCnt[i] = 0;
  if (bid == 0 && t < 128) p.gvec[t] = 0.f;
  if (bid == 0 && wv == 0) {
    float gb = wsum(p.gat_b[lane] * p.lin_W[lane]);
    if (lane == 0) *p.gbScalar = gb;
  }
  {  // combo: cA=sm[0..255], cD=sm[256..511], cZ=sm[512..767]
    float sa = 0.f, sd = 0.f, sz = 0.f;
#pragma unroll 8
    for (int k = 0; k < 64; k++) {
      float w = p.gat_W[t * 64 + k];
      sa += w * p.att_s[k]; sd += w * p.att_d[k]; sz += w * p.lin_W[k];
    }
    sm[t] = sa; sm[256 + t] = sd; sm[512 + t] = sz;
  }
  __syncthreads();
  for (int tile = bid; tile < NN / 16; tile += nb) {
#pragma unroll
    for (int j = 0; j < 4; j++) {
      int n = tile * 16 + wv * 4 + j;
      float e0 = p.embed[n * 128 + lane], e1 = p.embed[n * 128 + 64 + lane];
      float pA = wsum(e0 * sm[lane] + e1 * sm[64 + lane]);
      float qA = wsum(e0 * sm[128 + lane] + e1 * sm[192 + lane]);
      float pD = wsum(e0 * sm[256 + lane] + e1 * sm[320 + lane]);
      float qD = wsum(e0 * sm[384 + lane] + e1 * sm[448 + lane]);
      float pZ = wsum(e0 * sm[512 + lane] + e1 * sm[576 + lane]);
      float qZ = wsum(e0 * sm[640 + lane] + e1 * sm[704 + lane]);
      if (lane == 0) p.pN[n] = make_float4(pA, pD, pZ, 0.f);
      if (lane == 1) p.qN[n] = make_float4(qA, qD, qZ, 0.f);
    }
  }
  grid.sync();

  // ---- P1: per-edge scalars + col histogram ----
  for (int e = bid * 256 + t; e < EE; e += nb * 256) {
    int r = p.row[e], c = p.col[e];
    float4 pp = p.pN[r];
    float4 qq = p.qN[c];
    p.asz[e] = make_float2(pp.x + qq.x, pp.z + qq.z);  // {a_s, z}
    p.ad[e] = pp.y + qq.y;
    atomicAdd(&p.colCnt[c], 1);
  }
  grid.sync();

  // ---- P2: block 0 scans colCnt; blocks 1.. partition edge2 (atomic-free cells) ----
  if (bid == 0) {
    int* sd32 = (int*)sm;
    int beg = t * 32;
    int s = 0;
    for (int i = 0; i < 32; i++) s += p.colCnt[beg + i];
    sd32[t] = s;
    __syncthreads();
    for (int o = 1; o < 256; o <<= 1) {
      int v = (t >= o) ? sd32[t - o] : 0;
      __syncthreads();
      sd32[t] += v;
      __syncthreads();
    }
    int run = (t == 0) ? 0 : sd32[t - 1];
    for (int i = 0; i < 32; i++) {
      p.colOffs[beg + i] = run;
      p.colCur[beg + i] = run;
      run += p.colCnt[beg + i];
    }
    if (t == 255) p.colOffs[NN] = run;
  } else {
    unsigned* lcur = (unsigned*)sm;  // NBIN cursors
    for (int k = bid - 1; k < PB; k += nb - 1) {
      if (t < NBIN) lcur[t] = 0u;
      __syncthreads();
      int base0 = k * PCHUNK;
      for (int i = t * 4; i < PCHUNK; i += 1024) {
        int4 sv = *(const int4*)&p.src2[base0 + i];
        int4 dv = *(const int4*)&p.dst2[base0 + i];
        int ss[4] = {sv.x, sv.y, sv.z, sv.w};
        int dd[4] = {dv.x, dv.y, dv.z, dv.w};
#pragma unroll
        for (int u = 0; u < 4; u++) {
          int s = ss[u], d = dd[u];
          float2 az = p.asz[s];
          float ea = __expf(lrelu(az.x + p.ad[d]));
          unsigned pk = packh2(ea, ea * az.y);
          int b = d >> 9;
          unsigned r = atomicAdd(&lcur[b], 1u);  // LDS atomic (cheap)
          if (r < CAP) p.bucket[((size_t)k * NBIN + b) * CAP + r] = ((u64)(d & 511) << 32) | pk;
        }
      }
      __syncthreads();
      if (t < NBIN) p.cellCnt[k * NBIN + t] = (int)min(lcur[t], (unsigned)CAP);
      __syncthreads();
    }
  }
  grid.sync();

  // ---- P3: per-bin LDS reduce + gate + hash insert (dn never hits memory) ----
  for (int b = bid; b < NBIN; b += nb) {
    float* acc = (float*)sm;          // 512 x {denom, numer}
    int* ccol = (int*)(sm + 1024);    // PB cell counts
    for (int i = t; i < 1024; i += 256) acc[i] = 0.f;
    if (t < PB) ccol[t] = p.cellCnt[t * NBIN + b];
    __syncthreads();
    for (int idx = t; idx < PB * CAP; idx += 256) {
      int k = idx / CAP, i = idx - k * CAP;
      if (i < ccol[k]) {
        u64 en = p.bucket[((size_t)k * NBIN + b) * CAP + i];
        int local = (int)(en >> 32);
        unsigned pk = (unsigned)en;
        __half2 h = *reinterpret_cast<__half2*>(&pk);
        atomicAdd(&acc[2 * local], __low2float(h));
        atomicAdd(&acc[2 * local + 1], __high2float(h));
      }
    }
    __syncthreads();
    float gb = *p.gbScalar + p.lin_b[0];
    float itmp = 1.f / p.tmp[0];
    for (int i = t; i < 512; i += 256) {
      int e = b * 512 + i;
      float2 szv = p.asz[e];
      float eself = __expf(lrelu(szv.x + p.ad[e]));  // softmax shift-invariant
      float la = (acc[2 * i + 1] + eself * szv.y) / (acc[2 * i] + eself) + gb;
      float ns = p.noise[e];
      float g = (logf(ns) - log1pf(-ns) + la) * itmp;
      float gate = 1.f / (1.f + __expf(-g));
      int key = p.row[e] * NN + p.col[e];
      unsigned hi = ((unsigned)key * 2654435761u) >> 14 & HMASK;
      while (true) {
        int old = atomicCAS(&p.hKeys[hi], -1, key);
        if (old == -1 || old == key) break;
        hi = (hi + 1) & HMASK;
      }
      atomic_pk_add_f16(&p.hPair[hi], packh2(1.0f, gate));
    }
    __syncthreads();
  }
  grid.sync();

  // ---- P4: edge_w + CSR scatter ----
  for (int e = bid * 256 + t; e < EE; e += nb * 256) {
    int r = p.row[e], c = p.col[e];
    int s1 = hfind(p.hKeys, r * NN + c);
    unsigned u1 = p.hPair[s1];
    __half2 h1 = *reinterpret_cast<__half2*>(&u1);
    float cv = __low2float(h1), g1 = __high2float(h1);
    int s2 = hfind(p.hKeys, c * NN + r);
    float g2 = 0.f;
    if (s2 >= 0) {
      unsigned u2 = p.hPair[s2];
      g2 = __high2float(*reinterpret_cast<__half2*>(&u2));
    }
    float em = cv * 0.5f * (g1 + g2);
    float w = 1.f / (1.f + __expf(-em));
    int pos = atomicAdd(&p.colCur[c], 1);
    p.csrP[pos] = make_int2(r, __float_as_int(w));
  }
  grid.sync();

  // ---- P5..P7: 3 GCN layers (fused gather+GEMM; layer 3 pools in-block) ----
  float* Wl = (float*)sm;             // 64 KB
  float* Tl = (float*)(sm + 16384);   // 8 KB
  float* gpart = (float*)(sm + 18432);  // 512 B
#pragma unroll 1
  for (int L = 0; L < 3; L++) {
    const float* xh = (L == 0) ? p.x : (L == 1 ? p.H1 : p.H2);
    const float* W = (L == 0) ? p.W1 : (L == 1 ? p.W2 : p.W3);
    float* outH = (L == 0) ? p.H1 : p.H2;
    bool pool = (L == 2);
    for (int tile = bid; tile < NN / 16; tile += nb) {
      for (int i = t; i < 4096; i += 256) ((float4*)Wl)[i] = ((const float4*)W)[i];
      // gather (overlaps W staging; no sync needed until GEMM)
#pragma unroll
      for (int j = 0; j < 4; j++) {
        int n = tile * 16 + wv * 4 + j;
        float a0 = xh[n * 128 + lane], a1 = xh[n * 128 + 64 + lane];
        float ws = 0.f;
        int off = p.colOffs[n], end = p.colOffs[n + 1];
        for (int i = off; i < end; i++) {
          int2 q = p.csrP[i];
          float wgt = __int_as_float(q.y);
          ws += wgt;
          a0 += wgt * xh[q.x * 128 + lane];
          a1 += wgt * xh[q.x * 128 + 64 + lane];
        }
        float inv = 1.f / (1.f + ws);
        Tl[(wv * 4 + j) * 128 + lane] = a0 * inv;
        Tl[(wv * 4 + j) * 128 + 64 + lane] = a1 * inv;
      }
      __syncthreads();
      float2 acc[4];
#pragma unroll
      for (int j = 0; j < 4; j++) acc[j] = make_float2(0.f, 0.f);
      for (int k = 0; k < 128; k += 2) {
        float2 w0 = *(const float2*)&Wl[k * 128 + 2 * lane];
        float2 w1 = *(const float2*)&Wl[(k + 1) * 128 + 2 * lane];
#pragma unroll
        for (int j = 0; j < 4; j++) {
          float2 tv = *(const float2*)&Tl[(wv * 4 + j) * 128 + k];
          acc[j].x += tv.x * w0.x + tv.y * w1.x;
          acc[j].y += tv.x * w0.y + tv.y * w1.y;
        }
      }
      if (!pool) {
#pragma unroll
        for (int j = 0; j < 4; j++) {
          int n = tile * 16 + wv * 4 + j;
          *(float2*)&outH[n * 128 + 2 * lane] =
              make_float2(fmaxf(acc[j].x, 0.f), fmaxf(acc[j].y, 0.f));
        }
        __syncthreads();  // before next tile rewrites Wl/Tl
      } else {
        float s0 = 0.f, s1 = 0.f;
#pragma unroll
        for (int j = 0; j < 4; j++) {
          s0 += fmaxf(acc[j].x, 0.f);
          s1 += fmaxf(acc[j].y, 0.f);
        }
        __syncthreads();
        if (t < 128) gpart[t] = 0.f;
        __syncthreads();
        atomicAdd(&gpart[2 * lane], s0);
        atomicAdd(&gpart[2 * lane + 1], s1);
        __syncthreads();
        if (t < 128) atomicAdd(&p.gvec[t], gpart[t]);
        __syncthreads();
      }
    }
    grid.sync();
  }

  // ---- P8: final (block 0) ----
  if (bid == 0) {
    float* s0 = (float*)sm;
    float* s1 = s0 + 128;
    if (t < 128) {
      float gj = p.gvec[t] * (1.0f / 8192.0f);
      s0[t] = gj * p.Wc[t * 2 + 0];
      s1[t] = gj * p.Wc[t * 2 + 1];
    }
    __syncthreads();
    for (int o = 64; o > 0; o >>= 1) {
      if (t < o) { s0[t] += s0[t + o]; s1[t] += s1[t + o]; }
      __syncthreads();
    }
    if (t == 0) {
      float l0 = s0[0], l1 = s1[0];
      float m = fmaxf(l0, l1);
      float e0 = __expf(l0 - m), e1 = __expf(l1 - m);
      float inv = 1.f / (e0 + e1);
      p.out[0] = e0 * inv;
      p.out[1] = e1 * inv;
    }
  }
}

// ======================= FALLBACK (round-5 sequence) =======================
__global__ __launch_bounds__(256) void k_init(int* __restrict__ hKeys, unsigned* __restrict__ hPair,
                                              int* __restrict__ colCnt, float* __restrict__ gvec,
                                              unsigned* __restrict__ gCur) {
  int tid = blockIdx.x * 256 + threadIdx.x;
  hKeys[tid] = -1;
  hPair[tid] = 0u;
  if (tid < NN) colCnt[tid] = 0;
  if (tid < 128) gvec[tid] = 0.f;
  if (tid < NBIN) gCur[tid] = 0u;
}

__global__ __launch_bounds__(256) void k_combo(const float* __restrict__ gw,
                                               const float* __restrict__ att_s,
                                               const float* __restrict__ att_d,
                                               const float* __restrict__ lin_W,
                                               float* __restrict__ cA, float* __restrict__ cD,
                                               float* __restrict__ cZ) {
  int i = threadIdx.x;
  float sa = 0.f, sd = 0.f, sz = 0.f;
#pragma unroll 8
  for (int k = 0; k < 64; k++) {
    float w = gw[i * 64 + k];
    sa += w * att_s[k]; sd += w * att_d[k]; sz += w * lin_W[k];
  }
  cA[i] = sa; cD[i] = sd; cZ[i] = sz;
}

__global__ __launch_bounds__(256) void k_nodescal(const float* __restrict__ embed,
                                                  const float* __restrict__ cA,
                                                  const float* __restrict__ cD,
                                                  const float* __restrict__ cZ,
                                                  float4* __restrict__ pN, float4* __restrict__ qN) {
  int lane = threadIdx.x & 63;
  int n = blockIdx.x * 4 + (threadIdx.x >> 6);
  float e0 = embed[n * 128 + lane], e1 = embed[n * 128 + 64 + lane];
  float pA = wsum(e0 * cA[lane] + e1 * cA[64 + lane]);
  float qA = wsum(e0 * cA[128 + lane] + e1 * cA[192 + lane]);
  float pD = wsum(e0 * cD[lane] + e1 * cD[64 + lane]);
  float qD = wsum(e0 * cD[128 + lane] + e1 * cD[192 + lane]);
  float pZ = wsum(e0 * cZ[lane] + e1 * cZ[64 + lane]);
  float qZ = wsum(e0 * cZ[128 + lane] + e1 * cZ[192 + lane]);
  if (lane == 0) pN[n] = make_float4(pA, pD, pZ, 0.f);
  if (lane == 1) qN[n] = make_float4(qA, qD, qZ, 0.f);
}

__global__ void k_asd(const int* __restrict__ row, const int* __restrict__ col,
                      const float4* __restrict__ pN, const float4* __restrict__ qN,
                      float2* __restrict__ asz, float* __restrict__ ad, int* __restrict__ colCnt) {
  int e = blockIdx.x * 256 + threadIdx.x;
  int r = row[e], c = col[e];
  float4 p = pN[r];
  float4 q = qN[c];
  asz[e] = make_float2(p.x + q.x, p.z + q.z);
  ad[e] = p.y + q.y;
  atomicAdd(&colCnt[c], 1);
}

__global__ __launch_bounds__(256) void k_part(const int* __restrict__ src2, const int* __restrict__ dst2,
                                              const float2* __restrict__ asz, const float* __restrict__ ad,
                                              unsigned* __restrict__ gCur, u64* __restrict__ bucket) {
  __shared__ unsigned hist[NBIN], base[NBIN], lcur[NBIN];
  int t = threadIdx.x;
  if (t < NBIN) { hist[t] = 0u; lcur[t] = 0u; }
  __syncthreads();
  int blockBase = blockIdx.x * 4096;
  int4 dv[4];
#pragma unroll
  for (int j = 0; j < 4; j++) {
    dv[j] = *(const int4*)&dst2[blockBase + j * 1024 + t * 4];
    atomicAdd(&hist[dv[j].x >> 9], 1u);
    atomicAdd(&hist[dv[j].y >> 9], 1u);
    atomicAdd(&hist[dv[j].z >> 9], 1u);
    atomicAdd(&hist[dv[j].w >> 9], 1u);
  }
  __syncthreads();
  if (t < NBIN) base[t] = atomicAdd(&gCur[t], hist[t]);
  __syncthreads();
#pragma unroll
  for (int j = 0; j < 4; j++) {
    int4 sv = *(const int4*)&src2[blockBase + j * 1024 + t * 4];
    int ss[4] = {sv.x, sv.y, sv.z, sv.w};
    int dd[4] = {dv[j].x, dv[j].y, dv[j].z, dv[j].w};
#pragma unroll
    for (int k = 0; k < 4; k++) {
      int s = ss[k], d = dd[k];
      float2 az = asz[s];
      float ea = __expf(lrelu(az.x + ad[d]));
      unsigned pk = packh2(ea, ea * az.y);
      int b = d >> 9;
      unsigned r = atomicAdd(&lcur[b], 1u);
      bucket[(size_t)b * FB_BCAP + base[b] + r] = ((u64)(d & 511) << 32) | pk;
    }
  }
}

__global__ __launch_bounds__(256) void k_reduce(const u64* __restrict__ bucket,
                                                const unsigned* __restrict__ gCur,
                                                float2* __restrict__ dn) {
  __shared__ float acc[1024];
  int b = blockIdx.x, t = threadIdx.x;
  for (int i = t; i < 1024; i += 256) acc[i] = 0.f;
  __syncthreads();
  int cnt = (int)gCur[b];
  const u64* bp = bucket + (size_t)b * FB_BCAP;
  for (int i = t; i < cnt; i += 256) {
    u64 e = bp[i];
    int local = (int)(e >> 32);
    unsigned pk = (unsigned)e;
    __half2 h = *reinterpret_cast<__half2*>(&pk);
    atomicAdd(&acc[2 * local], __low2float(h));
    atomicAdd(&acc[2 * local + 1], __high2float(h));
  }
  __syncthreads();
  for (int i = t; i < 512; i += 256)
    dn[b * 512 + i] = make_float2(acc[2 * i], acc[2 * i + 1]);
}

__global__ __launch_bounds__(256) void k_gate_hash(const int* __restrict__ row, const int* __restrict__ col,
                                                   const float2* __restrict__ asz, const float* __restrict__ ad,
                                                   const float2* __restrict__ dn,
                                                   const float* __restrict__ gat_bias, const float* __restrict__ lin_W,
                                                   const float* __restrict__ lin_b, const float* __restrict__ noise,
                                                   const float* __restrict__ tmp,
                                                   int* __restrict__ keys, unsigned* __restrict__ hPairU) {
  int lane = threadIdx.x & 63;
  float gb = wsum(gat_bias[lane] * lin_W[lane]);
  int e = blockIdx.x * 256 + threadIdx.x;
  float2 sz = asz[e];
  float eself = __expf(lrelu(sz.x + ad[e]));
  float2 dnv = dn[e];
  float la = (dnv.y + eself * sz.y) / (dnv.x + eself) + gb + lin_b[0];
  float ns = noise[e];
  float g = (logf(ns) - log1pf(-ns) + la) / tmp[0];
  float gate = 1.0f / (1.0f + __expf(-g));
  int key = row[e] * NN + col[e];
  unsigned i = ((unsigned)key * 2654435761u) >> 14 & HMASK;
  while (true) {
    int old = atomicCAS(&keys[i], -1, key);
    if (old == -1 || old == key) break;
    i = (i + 1) & HMASK;
  }
  atomic_pk_add_f16(&hPairU[i], packh2(1.0f, gate));
}

__global__ void k_edge_w(const int* __restrict__ row, const int* __restrict__ col,
                         const int* __restrict__ keys, const unsigned* __restrict__ hPairU,
                         int* __restrict__ colCur, int2* __restrict__ csrP) {
  int e = blockIdx.x * 256 + threadIdx.x;
  if (e >= EE) return;
  int r = row[e], c = col[e];
  int s1 = hfind(keys, r * NN + c);
  unsigned u1 = hPairU[s1];
  __half2 h1 = *reinterpret_cast<__half2*>(&u1);
  float cv = __low2float(h1), g1 = __high2float(h1);
  int s2 = hfind(keys, c * NN + r);
  float g2 = 0.f;
  if (s2 >= 0) {
    unsigned u2 = hPairU[s2];
    g2 = __high2float(*reinterpret_cast<__half2*>(&u2));
  }
  float em = cv * 0.5f * (g1 + g2);
  float w = 1.f / (1.f + __expf(-em));
  int pos = atomicAdd(&colCur[c], 1);
  csrP[pos] = make_int2(r, __float_as_int(w));
}

__global__ __launch_bounds__(1024) void k_scan(const int* __restrict__ cnt, int n,
                                               int* __restrict__ offs, int* __restrict__ cur) {
  __shared__ int sd[1024];
  int t = threadIdx.x;
  int C = (n + 1023) >> 10;
  int beg = t * C, end = min(beg + C, n);
  int s = 0;
  for (int i = beg; i < end; i++) s += cnt[i];
  sd[t] = s;
  __syncthreads();
  for (int off = 1; off < 1024; off <<= 1) {
    int v = (t >= off) ? sd[t - off] : 0;
    __syncthreads();
    sd[t] += v;
    __syncthreads();
  }
  int run = (t == 0) ? 0 : sd[t - 1];
  for (int i = beg; i < end; i++) {
    offs[i] = run;
    cur[i] = run;
    run += cnt[i];
  }
  if (t == 0) offs[n] = sd[1023];
}

__global__ __launch_bounds__(256) void k_layer(const float* __restrict__ xh,
                                               const int* __restrict__ colOffs,
                                               const int2* __restrict__ csrP,
                                               const float* __restrict__ W,
                                               float* __restrict__ outH) {
  __shared__ float Wl[128 * 128];
  __shared__ float Tl[16 * 128];
  for (int i = threadIdx.x; i < 4096; i += 256)
    ((float4*)Wl)[i] = ((const float4*)W)[i];
  int lane = threadIdx.x & 63;
  int wv = threadIdx.x >> 6;
  int nb = blockIdx.x * 16;
#pragma unroll
  for (int j = 0; j < 4; j++) {
    int n = nb + wv * 4 + j;
    float a0 = xh[n * 128 + lane], a1 = xh[n * 128 + 64 + lane];
    float ws = 0.f;
    int off = colOffs[n], end = colOffs[n + 1];
    for (int i = off; i < end; i++) {
      int2 q = csrP[i];
      float wgt = __int_as_float(q.y);
      ws += wgt;
      a0 += wgt * xh[q.x * 128 + lane];
      a1 += wgt * xh[q.x * 128 + 64 + lane];
    }
    float inv = 1.f / (1.f + ws);
    Tl[(wv * 4 + j) * 128 + lane] = a0 * inv;
    Tl[(wv * 4 + j) * 128 + 64 + lane] = a1 * inv;
  }
  __syncthreads();
  float2 acc[4];
#pragma unroll
  for (int j = 0; j < 4; j++) acc[j] = make_float2(0.f, 0.f);
  for (int k = 0; k < 128; k += 2) {
    float2 w0 = *(const float2*)&Wl[k * 128 + 2 * lane];
    float2 w1 = *(const float2*)&Wl[(k + 1) * 128 + 2 * lane];
#pragma unroll
    for (int j = 0; j < 4; j++) {
      float2 tv = *(const float2*)&Tl[(wv * 4 + j) * 128 + k];
      acc[j].x += tv.x * w0.x + tv.y * w1.x;
      acc[j].y += tv.x * w0.y + tv.y * w1.y;
    }
  }
#pragma unroll
  for (int j = 0; j < 4; j++) {
    int n = nb + wv * 4 + j;
    *(float2*)&outH[n * 128 + 2 * lane] =
        make_float2(fmaxf(acc[j].x, 0.f), fmaxf(acc[j].y, 0.f));
  }
}

__global__ __launch_bounds__(256) void k_pool(const float* __restrict__ H, float* __restrict__ gvec) {
  int t = threadIdx.x;
  int d = t & 127;
  int h = t >> 7;
  int base = blockIdx.x * 64;
  float s = 0.f;
  for (int n = base + h; n < base + 64; n += 2) s += H[n * 128 + d];
  __shared__ float sd[256];
  sd[t] = s;
  __syncthreads();
  if (h == 0) atomicAdd(&gvec[d], sd[t] + sd[t + 128]);
}

__global__ __launch_bounds__(128) void k_final(const float* __restrict__ gvec, const float* __restrict__ Wc,
                                               float* __restrict__ out) {
  int j = threadIdx.x;
  float gj = gvec[j] * (1.0f / 8192.0f);
  __shared__ float s0[128], s1[128];
  s0[j] = gj * Wc[j * 2 + 0];
  s1[j] = gj * Wc[j * 2 + 1];
  __syncthreads();
  for (int o = 64; o > 0; o >>= 1) {
    if (j < o) { s0[j] += s0[j + o]; s1[j] += s1[j + o]; }
    __syncthreads();
  }
  if (j == 0) {
    float l0 = s0[0], l1 = s1[0];
    float m = fmaxf(l0, l1);
    float e0 = expf(l0 - m), e1 = expf(l1 - m);
    float inv = 1.f / (e0 + e1);
    out[0] = e0 * inv;
    out[1] = e1 * inv;
  }
}

extern "C" void kernel_launch(void* const* d_in, const int* in_sizes, int n_in,
                              void* d_out, int out_size, void* d_ws, size_t ws_size,
                              hipStream_t stream) {
  const float* x     = (const float*)d_in[0];
  const float* embed = (const float*)d_in[1];
  const float* noise = (const float*)d_in[2];
  const float* tmp   = (const float*)d_in[3];
  const float* gat_W = (const float*)d_in[4];
  const float* att_s = (const float*)d_in[5];
  const float* att_d = (const float*)d_in[6];
  const float* gat_b = (const float*)d_in[7];
  const float* lin_W = (const float*)d_in[8];
  const float* lin_b = (const float*)d_in[9];
  const float* W1    = (const float*)d_in[10];
  const float* W2    = (const float*)d_in[11];
  const float* W3    = (const float*)d_in[12];
  const float* Wc    = (const float*)d_in[13];
  const int* ei      = (const int*)d_in[14];
  const int* nei     = (const int*)d_in[15];
  const int* row = ei;
  const int* col = ei + EE;
  const int* src2 = nei;
  const int* dst2 = nei + E2C;
  float* out = (float*)d_out;

  // workspace layout (4-byte units); 16B/8B-aligned buffers first
  char* w8 = (char*)d_ws;
  size_t off = 0;
  auto alloc = [&](size_t units) -> void* {
    void* p = w8 + off * 4;
    off += units;
    return p;
  };
  float4* pN    = (float4*)alloc(4 * NN);
  float4* qN    = (float4*)alloc(4 * NN);
  float2* asz   = (float2*)alloc(2 * EE);
  float2* dn    = (float2*)alloc(2 * EE);          // fallback only
  int2*   csrP  = (int2*)alloc(2 * EE);
  u64*    bucket = (u64*)alloc(2 * (size_t)PB * NBIN * CAP);  // 26.2 MB (aliases fallback's 23.6 MB)
  float*  ad    = (float*)alloc(EE);
  int*    colCnt = (int*)alloc(NN);
  float*  gvec  = (float*)alloc(128);
  unsigned* gCur = (unsigned*)alloc(NBIN + 96);    // fallback only
  int*    colCur = (int*)alloc(NN);
  int*    colOffs = (int*)alloc(NN + 2);
  int*    hKeys = (int*)alloc(HSZ);
  unsigned* hPair = (unsigned*)alloc(HSZ);
  int*    cellCnt = (int*)alloc(PB * NBIN);
  float*  gbScalar = (float*)alloc(2);
  float*  cA    = (float*)alloc(256);              // fallback only
  float*  cD    = (float*)alloc(256);
  float*  cZ    = (float*)alloc(256);
  float*  H1    = (float*)alloc(NN * 128);
  float*  H2    = (float*)alloc(NN * 128);

  KP kp;
  kp.x = x; kp.embed = embed; kp.noise = noise; kp.tmp = tmp; kp.gat_W = gat_W;
  kp.att_s = att_s; kp.att_d = att_d; kp.gat_b = gat_b; kp.lin_W = lin_W; kp.lin_b = lin_b;
  kp.W1 = W1; kp.W2 = W2; kp.W3 = W3; kp.Wc = Wc;
  kp.row = row; kp.col = col; kp.src2 = src2; kp.dst2 = dst2;
  kp.out = out;
  kp.pN = pN; kp.qN = qN; kp.asz = asz; kp.ad = ad;
  kp.colCnt = colCnt; kp.colOffs = colOffs; kp.colCur = colCur;
  kp.hKeys = hKeys; kp.hPair = hPair;
  kp.bucket = bucket; kp.cellCnt = cellCnt;
  kp.gvec = gvec; kp.gbScalar = gbScalar;
  kp.H1 = H1; kp.H2 = H2; kp.csrP = csrP;

  int occ = 0;
  hipError_t oe = hipOccupancyMaxActiveBlocksPerMultiprocessor(&occ, mega, 256, 0);
  int grid = (oe == hipSuccess && occ >= 1) ? (occ >= 2 ? 512 : 256) : 0;

  hipError_t err = hipErrorUnknown;
  if (grid > 0) {
    void* args[] = { (void*)&kp };
    err = hipLaunchCooperativeKernel((const void*)mega, dim3(grid), dim3(256), args, 0, stream);
  }
  if (err != hipSuccess) {
    // -------- fallback: round-5 multi-kernel sequence --------
    k_init<<<HSZ / 256, 256, 0, stream>>>(hKeys, hPair, colCnt, gvec, gCur);
    k_combo<<<1, 256, 0, stream>>>(gat_W, att_s, att_d, lin_W, cA, cD, cZ);
    k_nodescal<<<NN / 4, 256, 0, stream>>>(embed, cA, cD, cZ, pN, qN);
    k_asd<<<EE / 256, 256, 0, stream>>>(row, col, pN, qN, asz, ad, colCnt);
    k_scan<<<1, 1024, 0, stream>>>(colCnt, NN, colOffs, colCur);
    k_part<<<E2C / 4096, 256, 0, stream>>>(src2, dst2, asz, ad, gCur, bucket);
    k_reduce<<<NBIN, 256, 0, stream>>>(bucket, gCur, dn);
    k_gate_hash<<<EE / 256, 256, 0, stream>>>(row, col, asz, ad, dn, gat_b, lin_W,
                                              lin_b, noise, tmp, hKeys, hPair);
    k_edge_w<<<EE / 256, 256, 0, stream>>>(row, col, hKeys, hPair, colCur, csrP);
    k_layer<<<NN / 16, 256, 0, stream>>>(x, colOffs, csrP, W1, H1);
    k_layer<<<NN / 16, 256, 0, stream>>>(H1, colOffs, csrP, W2, H2);
    k_layer<<<NN / 16, 256, 0, stream>>>(H2, colOffs, csrP, W3, H1);
    k_pool<<<NN / 64, 256, 0, stream>>>(H1, gvec);
    k_final<<<1, 128, 0, stream>>>(gvec, Wc, out);
  }
}

// Round 7
// 268.836 us; speedup vs baseline: 2.8213x; 2.8213x over previous
//
#include <hip/hip_runtime.h>
#include <hip/hip_fp16.h>
#include <math.h>

typedef unsigned long long u64;

#define NN 8192
#define EE 81920
#define E2C 1310720
#define HSZ (1 << 18)
#define HMASK (HSZ - 1)
#define NBIN 320     // dst >> 8 : bins of 256 edge-nodes
#define BCAP 4800    // Poisson(4096), +11 sigma
#define SBITS 17     // src index bits in packed u32 payload

__device__ __forceinline__ float wsum(float v) {
#pragma unroll
  for (int m = 32; m > 0; m >>= 1) v += __shfl_xor(v, m, 64);
  return v;
}
__device__ __forceinline__ float lrelu(float x) { return x > 0.f ? x : 0.2f * x; }
__device__ __forceinline__ unsigned packh2(float a, float b) {
  __half2 h = __floats2half2_rn(a, b);
  return *reinterpret_cast<unsigned*>(&h);
}
__device__ __forceinline__ void atomic_pk_add_f16(unsigned* addr, unsigned data) {
  asm volatile("global_atomic_pk_add_f16 %0, %1, off" :: "v"(addr), "v"(data) : "memory");
}
__device__ __forceinline__ int hfind(const int* __restrict__ keys, int key) {
  unsigned i = ((unsigned)key * 2654435761u) >> 14 & HMASK;
  while (true) {
    int k = keys[i];
    if (k == key) return (int)i;
    if (k == -1) return -1;
    i = (i + 1) & HMASK;
  }
}

// A: init (hash/colCnt/gvec/done/gCur) + per-block combo in LDS + node scalars.
// 512 blocks x 16 nodes.
__global__ __launch_bounds__(256) void kA(const float* __restrict__ embed,
                                          const float* __restrict__ gw,
                                          const float* __restrict__ att_s,
                                          const float* __restrict__ att_d,
                                          const float* __restrict__ lin_W,
                                          float4* __restrict__ pN, float4* __restrict__ qN,
                                          int* __restrict__ hKeys, unsigned* __restrict__ hPair,
                                          int* __restrict__ colCnt, float* __restrict__ gvec,
                                          unsigned* __restrict__ done, unsigned* __restrict__ gCur) {
  __shared__ float sm[768];  // cA | cD | cZ
  int t = threadIdx.x, bid = blockIdx.x;
  int lane = t & 63, wv = t >> 6;
  for (int i = bid * 256 + t; i < HSZ; i += 512 * 256) { hKeys[i] = -1; hPair[i] = 0u; }
  for (int i = bid * 256 + t; i < NN; i += 512 * 256) colCnt[i] = 0;
  if (bid == 0) {
    if (t < 128) gvec[t] = 0.f;
    if (t == 0) *done = 0u;
    if (t < NBIN) gCur[t] = 0u;
  }
  {
    float sa = 0.f, sd = 0.f, sz = 0.f;
#pragma unroll 8
    for (int k = 0; k < 64; k++) {
      float w = gw[t * 64 + k];
      sa += w * att_s[k]; sd += w * att_d[k]; sz += w * lin_W[k];
    }
    sm[t] = sa; sm[256 + t] = sd; sm[512 + t] = sz;
  }
  __syncthreads();
#pragma unroll
  for (int j = 0; j < 4; j++) {
    int n = bid * 16 + wv * 4 + j;
    float e0 = embed[n * 128 + lane], e1 = embed[n * 128 + 64 + lane];
    float pA = wsum(e0 * sm[lane] + e1 * sm[64 + lane]);
    float qA = wsum(e0 * sm[128 + lane] + e1 * sm[192 + lane]);
    float pD = wsum(e0 * sm[256 + lane] + e1 * sm[320 + lane]);
    float qD = wsum(e0 * sm[384 + lane] + e1 * sm[448 + lane]);
    float pZ = wsum(e0 * sm[512 + lane] + e1 * sm[576 + lane]);
    float qZ = wsum(e0 * sm[640 + lane] + e1 * sm[704 + lane]);
    if (lane == 0) pN[n] = make_float4(pA, pD, pZ, 0.f);
    if (lane == 1) qN[n] = make_float4(qA, qD, qZ, 0.f);
  }
}

// B: per-edge scalars + col histogram
__global__ void kB(const int* __restrict__ row, const int* __restrict__ col,
                   const float4* __restrict__ pN, const float4* __restrict__ qN,
                   float2* __restrict__ asz, float* __restrict__ ad, int* __restrict__ colCnt) {
  int e = blockIdx.x * 256 + threadIdx.x;
  int r = row[e], c = col[e];
  float4 p = pN[r];
  float4 q = qN[c];
  asz[e] = make_float2(p.x + q.x, p.z + q.z);  // {a_s, z}
  ad[e] = p.y + q.y;
  atomicAdd(&colCnt[c], 1);
}

// C: blocks 0..319 partition edge2 into 320 dst bins (u32 payload (local<<17)|src);
//    block 320 runs the col-CSR scan concurrently (disjoint data, no sync needed).
__global__ __launch_bounds__(256) void kC(const int* __restrict__ src2, const int* __restrict__ dst2,
                                          const int* __restrict__ colCnt, int* __restrict__ colOffs,
                                          int* __restrict__ colCur,
                                          unsigned* __restrict__ gCur, unsigned* __restrict__ bucket) {
  int t = threadIdx.x;
  if (blockIdx.x == 320) {  // exclusive scan of colCnt (8192)
    __shared__ int sd32[256];
    int beg = t * 32;
    int s = 0;
#pragma unroll 8
    for (int i = 0; i < 32; i++) s += colCnt[beg + i];
    sd32[t] = s;
    __syncthreads();
    for (int o = 1; o < 256; o <<= 1) {
      int v = (t >= o) ? sd32[t - o] : 0;
      __syncthreads();
      sd32[t] += v;
      __syncthreads();
    }
    int run = (t == 0) ? 0 : sd32[t - 1];
    for (int i = 0; i < 32; i++) {
      colOffs[beg + i] = run;
      colCur[beg + i] = run;
      run += colCnt[beg + i];
    }
    if (t == 255) colOffs[NN] = run;
    return;
  }
  __shared__ unsigned hist[NBIN], base[NBIN], lcur[NBIN];
  if (t < 256) { }  // (NBIN=320 > 256: strided init)
  for (int i = t; i < NBIN; i += 256) { hist[i] = 0u; lcur[i] = 0u; }
  __syncthreads();
  int blockBase = blockIdx.x * 4096;
  int4 dv[4];
#pragma unroll
  for (int j = 0; j < 4; j++) {
    dv[j] = *(const int4*)&dst2[blockBase + j * 1024 + t * 4];
    atomicAdd(&hist[dv[j].x >> 8], 1u);
    atomicAdd(&hist[dv[j].y >> 8], 1u);
    atomicAdd(&hist[dv[j].z >> 8], 1u);
    atomicAdd(&hist[dv[j].w >> 8], 1u);
  }
  __syncthreads();
  for (int i = t; i < NBIN; i += 256)
    if (hist[i]) base[i] = atomicAdd(&gCur[i], hist[i]);
  __syncthreads();
#pragma unroll
  for (int j = 0; j < 4; j++) {
    int4 sv = *(const int4*)&src2[blockBase + j * 1024 + t * 4];
    int ss[4] = {sv.x, sv.y, sv.z, sv.w};
    int dd[4] = {dv[j].x, dv[j].y, dv[j].z, dv[j].w};
#pragma unroll
    for (int k = 0; k < 4; k++) {
      int s = ss[k], d = dd[k];
      int b = d >> 8;
      unsigned r = atomicAdd(&lcur[b], 1u);
      unsigned pos = base[b] + r;
      if (pos < BCAP) bucket[(size_t)b * BCAP + pos] = ((unsigned)(d & 255) << SBITS) | (unsigned)s;
    }
  }
}

// D: per-bin reduce (re-derive exp from packed src) + gate + hash insert (dn stays in LDS)
__global__ __launch_bounds__(256) void kD(const int* __restrict__ row, const int* __restrict__ col,
                                          const float2* __restrict__ asz, const float* __restrict__ ad,
                                          const unsigned* __restrict__ bucket, const unsigned* __restrict__ gCur,
                                          const float* __restrict__ gat_b, const float* __restrict__ lin_W,
                                          const float* __restrict__ lin_b, const float* __restrict__ noise,
                                          const float* __restrict__ tmp,
                                          int* __restrict__ hKeys, unsigned* __restrict__ hPair) {
  __shared__ float acc[512];  // 256 dsts x {denom, numer}
  __shared__ float adl[256];
  int b = blockIdx.x, t = threadIdx.x, lane = t & 63;
  if (t < 256) { acc[2 * t] = 0.f; acc[2 * t + 1] = 0.f; adl[t] = ad[b * 256 + t]; }
  __syncthreads();
  int cnt = min((int)gCur[b], BCAP);
  const unsigned* bp = bucket + (size_t)b * BCAP;
  for (int i = t; i < cnt; i += 256) {
    unsigned u = bp[i];
    int s = (int)(u & ((1u << SBITS) - 1));
    int local = (int)(u >> SBITS);
    float2 az = asz[s];
    float ea = __expf(lrelu(az.x + adl[local]));
    atomicAdd(&acc[2 * local], ea);
    atomicAdd(&acc[2 * local + 1], ea * az.y);
  }
  __syncthreads();
  float gb = wsum(gat_b[lane] * lin_W[lane]) + lin_b[0];
  float itmp = 1.f / tmp[0];
  {
    int i = t;  // one edge per thread (256 per bin)
    int e = b * 256 + i;
    float2 szv = asz[e];
    float eself = __expf(lrelu(szv.x + adl[i]));  // softmax shift-invariant
    float la = (acc[2 * i + 1] + eself * szv.y) / (acc[2 * i] + eself) + gb;
    float ns = noise[e];
    float g = (logf(ns) - log1pf(-ns) + la) * itmp;
    float gate = 1.f / (1.f + __expf(-g));
    int key = row[e] * NN + col[e];
    unsigned hi = ((unsigned)key * 2654435761u) >> 14 & HMASK;
    while (true) {
      int old = atomicCAS(&hKeys[hi], -1, key);
      if (old == -1 || old == key) break;
      hi = (hi + 1) & HMASK;
    }
    atomic_pk_add_f16(&hPair[hi], packh2(1.0f, gate));
  }
}

// E: edge_mask -> w; CSR scatter of packed (row, w)
__global__ void kE(const int* __restrict__ row, const int* __restrict__ col,
                   const int* __restrict__ hKeys, const unsigned* __restrict__ hPair,
                   int* __restrict__ colCur, int2* __restrict__ csrP) {
  int e = blockIdx.x * 256 + threadIdx.x;
  int r = row[e], c = col[e];
  int s1 = hfind(hKeys, r * NN + c);
  unsigned u1 = hPair[s1];
  __half2 h1 = *reinterpret_cast<__half2*>(&u1);
  float cv = __low2float(h1), g1 = __high2float(h1);
  int s2 = hfind(hKeys, c * NN + r);
  float g2 = 0.f;
  if (s2 >= 0) {
    unsigned u2 = hPair[s2];
    g2 = __high2float(*reinterpret_cast<__half2*>(&u2));
  }
  float em = cv * 0.5f * (g1 + g2);
  float w = 1.f / (1.f + __expf(-em));
  int pos = atomicAdd(&colCur[c], 1);
  csrP[pos] = make_int2(r, __float_as_int(w));
}

// F: GCN layer (gather overlapped with W staging + 128x128 GEMM + relu), 16 nodes/block
__global__ __launch_bounds__(256) void kF(const float* __restrict__ xh,
                                          const int* __restrict__ colOffs,
                                          const int2* __restrict__ csrP,
                                          const float* __restrict__ W,
                                          float* __restrict__ outH) {
  __shared__ float Wl[128 * 128];
  __shared__ float Tl[16 * 128];
  for (int i = threadIdx.x; i < 4096; i += 256)
    ((float4*)Wl)[i] = ((const float4*)W)[i];
  int lane = threadIdx.x & 63;
  int wv = threadIdx.x >> 6;
  int nb = blockIdx.x * 16;
#pragma unroll
  for (int j = 0; j < 4; j++) {
    int n = nb + wv * 4 + j;
    float a0 = xh[n * 128 + lane], a1 = xh[n * 128 + 64 + lane];
    float ws = 0.f;
    int off = colOffs[n], end = colOffs[n + 1];
    if (off < end) {
      int2 q = csrP[off];
      for (int i = off + 1; i <= end; i++) {
        int2 qn = (i < end) ? csrP[i] : q;  // prefetch next entry
        float wgt = __int_as_float(q.y);
        ws += wgt;
        a0 += wgt * xh[q.x * 128 + lane];
        a1 += wgt * xh[q.x * 128 + 64 + lane];
        q = qn;
      }
    }
    float inv = 1.f / (1.f + ws);
    Tl[(wv * 4 + j) * 128 + lane] = a0 * inv;
    Tl[(wv * 4 + j) * 128 + 64 + lane] = a1 * inv;
  }
  __syncthreads();
  float2 acc[4];
#pragma unroll
  for (int j = 0; j < 4; j++) acc[j] = make_float2(0.f, 0.f);
  for (int k = 0; k < 128; k += 2) {
    float2 w0 = *(const float2*)&Wl[k * 128 + 2 * lane];
    float2 w1 = *(const float2*)&Wl[(k + 1) * 128 + 2 * lane];
#pragma unroll
    for (int j = 0; j < 4; j++) {
      float2 tv = *(const float2*)&Tl[(wv * 4 + j) * 128 + k];
      acc[j].x += tv.x * w0.x + tv.y * w1.x;
      acc[j].y += tv.x * w0.y + tv.y * w1.y;
    }
  }
#pragma unroll
  for (int j = 0; j < 4; j++) {
    int n = nb + wv * 4 + j;
    *(float2*)&outH[n * 128 + 2 * lane] =
        make_float2(fmaxf(acc[j].x, 0.f), fmaxf(acc[j].y, 0.f));
  }
}

// H: layer3 + pool + final (done-counter; last block reads gvec via memory-side atomics)
__global__ __launch_bounds__(256) void kH(const float* __restrict__ xh,
                                          const int* __restrict__ colOffs,
                                          const int2* __restrict__ csrP,
                                          const float* __restrict__ W,
                                          const float* __restrict__ Wc,
                                          float* __restrict__ gvec, unsigned* __restrict__ done,
                                          float* __restrict__ out) {
  __shared__ float Wl[128 * 128];
  __shared__ float Tl[16 * 128];
  __shared__ float gpart[128];
  __shared__ unsigned lastFlag;
  int t = threadIdx.x;
  for (int i = t; i < 4096; i += 256)
    ((float4*)Wl)[i] = ((const float4*)W)[i];
  int lane = t & 63;
  int wv = t >> 6;
  int nb = blockIdx.x * 16;
#pragma unroll
  for (int j = 0; j < 4; j++) {
    int n = nb + wv * 4 + j;
    float a0 = xh[n * 128 + lane], a1 = xh[n * 128 + 64 + lane];
    float ws = 0.f;
    int off = colOffs[n], end = colOffs[n + 1];
    if (off < end) {
      int2 q = csrP[off];
      for (int i = off + 1; i <= end; i++) {
        int2 qn = (i < end) ? csrP[i] : q;
        float wgt = __int_as_float(q.y);
        ws += wgt;
        a0 += wgt * xh[q.x * 128 + lane];
        a1 += wgt * xh[q.x * 128 + 64 + lane];
        q = qn;
      }
    }
    float inv = 1.f / (1.f + ws);
    Tl[(wv * 4 + j) * 128 + lane] = a0 * inv;
    Tl[(wv * 4 + j) * 128 + 64 + lane] = a1 * inv;
  }
  __syncthreads();
  float2 acc[4];
#pragma unroll
  for (int j = 0; j < 4; j++) acc[j] = make_float2(0.f, 0.f);
  for (int k = 0; k < 128; k += 2) {
    float2 w0 = *(const float2*)&Wl[k * 128 + 2 * lane];
    float2 w1 = *(const float2*)&Wl[(k + 1) * 128 + 2 * lane];
#pragma unroll
    for (int j = 0; j < 4; j++) {
      float2 tv = *(const float2*)&Tl[(wv * 4 + j) * 128 + k];
      acc[j].x += tv.x * w0.x + tv.y * w1.x;
      acc[j].y += tv.x * w0.y + tv.y * w1.y;
    }
  }
  // pool: H3 never written to memory
  float s0 = 0.f, s1 = 0.f;
#pragma unroll
  for (int j = 0; j < 4; j++) {
    s0 += fmaxf(acc[j].x, 0.f);
    s1 += fmaxf(acc[j].y, 0.f);
  }
  if (t < 128) gpart[t] = 0.f;
  __syncthreads();
  atomicAdd(&gpart[2 * lane], s0);
  atomicAdd(&gpart[2 * lane + 1], s1);
  __syncthreads();
  if (t < 128) atomicAdd(&gvec[t], gpart[t]);
  __threadfence();
  __syncthreads();
  if (t == 0) lastFlag = (atomicAdd(done, 1u) == gridDim.x - 1) ? 1u : 0u;
  __syncthreads();
  if (lastFlag) {
    float* f0 = Tl;
    float* f1 = Tl + 128;
    if (t < 128) {
      float gj = atomicAdd(&gvec[t], 0.f) * (1.0f / 8192.0f);  // memory-side read
      f0[t] = gj * Wc[t * 2 + 0];
      f1[t] = gj * Wc[t * 2 + 1];
    }
    __syncthreads();
    for (int o = 64; o > 0; o >>= 1) {
      if (t < o) { f0[t] += f0[t + o]; f1[t] += f1[t + o]; }
      __syncthreads();
    }
    if (t == 0) {
      float l0 = f0[0], l1 = f1[0];
      float m = fmaxf(l0, l1);
      float e0 = __expf(l0 - m), e1 = __expf(l1 - m);
      float inv = 1.f / (e0 + e1);
      out[0] = e0 * inv;
      out[1] = e1 * inv;
    }
  }
}

extern "C" void kernel_launch(void* const* d_in, const int* in_sizes, int n_in,
                              void* d_out, int out_size, void* d_ws, size_t ws_size,
                              hipStream_t stream) {
  const float* x     = (const float*)d_in[0];
  const float* embed = (const float*)d_in[1];
  const float* noise = (const float*)d_in[2];
  const float* tmp   = (const float*)d_in[3];
  const float* gat_W = (const float*)d_in[4];
  const float* att_s = (const float*)d_in[5];
  const float* att_d = (const float*)d_in[6];
  const float* gat_b = (const float*)d_in[7];
  const float* lin_W = (const float*)d_in[8];
  const float* lin_b = (const float*)d_in[9];
  const float* W1    = (const float*)d_in[10];
  const float* W2    = (const float*)d_in[11];
  const float* W3    = (const float*)d_in[12];
  const float* Wc    = (const float*)d_in[13];
  const int* ei      = (const int*)d_in[14];
  const int* nei     = (const int*)d_in[15];
  const int* row = ei;
  const int* col = ei + EE;
  const int* src2 = nei;
  const int* dst2 = nei + E2C;
  float* out = (float*)d_out;

  // workspace layout (4-byte units); 16B/8B-aligned buffers first
  char* w8 = (char*)d_ws;
  size_t off = 0;
  auto alloc = [&](size_t units) -> void* {
    void* p = w8 + off * 4;
    off += units;
    return p;
  };
  float4*   pN      = (float4*)alloc(4 * NN);
  float4*   qN      = (float4*)alloc(4 * NN);
  float2*   asz     = (float2*)alloc(2 * EE);
  int2*     csrP    = (int2*)alloc(2 * EE);
  float*    ad      = (float*)alloc(EE);
  int*      colCnt  = (int*)alloc(NN);
  int*      colOffs = (int*)alloc(NN + 2);
  int*      colCur  = (int*)alloc(NN);
  int*      hKeys   = (int*)alloc(HSZ);
  unsigned* hPair   = (unsigned*)alloc(HSZ);
  unsigned* bucket  = (unsigned*)alloc((size_t)NBIN * BCAP);
  unsigned* gCur    = (unsigned*)alloc(NBIN);
  float*    gvec    = (float*)alloc(128);
  unsigned* done    = (unsigned*)alloc(2);
  float*    H1      = (float*)alloc(NN * 128);
  float*    H2      = (float*)alloc(NN * 128);

  kA<<<512, 256, 0, stream>>>(embed, gat_W, att_s, att_d, lin_W, pN, qN,
                              hKeys, hPair, colCnt, gvec, done, gCur);
  kB<<<EE / 256, 256, 0, stream>>>(row, col, pN, qN, asz, ad, colCnt);
  kC<<<321, 256, 0, stream>>>(src2, dst2, colCnt, colOffs, colCur, gCur, bucket);
  kD<<<NBIN, 256, 0, stream>>>(row, col, asz, ad, bucket, gCur, gat_b, lin_W,
                               lin_b, noise, tmp, hKeys, hPair);
  kE<<<EE / 256, 256, 0, stream>>>(row, col, hKeys, hPair, colCur, csrP);
  kF<<<NN / 16, 256, 0, stream>>>(x, colOffs, csrP, W1, H1);
  kF<<<NN / 16, 256, 0, stream>>>(H1, colOffs, csrP, W2, H2);
  kH<<<NN / 16, 256, 0, stream>>>(H2, colOffs, csrP, W3, Wc, gvec, done, out);
}

// Round 8
// 249.055 us; speedup vs baseline: 3.0454x; 1.0794x over previous
//
#include <hip/hip_runtime.h>
#include <hip/hip_fp16.h>
#include <math.h>

typedef unsigned long long u64;

#define NN 8192
#define EE 81920
#define E2C 1310720
#define HSZ (1 << 18)
#define HMASK (HSZ - 1)
#define NBIN 320     // dst >> 8 : bins of 256 edge-nodes
#define BCAP 4800    // Poisson(4096), +11 sigma
#define SBITS 17     // src index bits in packed u32 payload

__device__ __forceinline__ float wsum(float v) {
#pragma unroll
  for (int m = 32; m > 0; m >>= 1) v += __shfl_xor(v, m, 64);
  return v;
}
__device__ __forceinline__ float lrelu(float x) { return x > 0.f ? x : 0.2f * x; }
__device__ __forceinline__ unsigned packh2(float a, float b) {
  __half2 h = __floats2half2_rn(a, b);
  return *reinterpret_cast<unsigned*>(&h);
}
__device__ __forceinline__ void atomic_pk_add_f16(unsigned* addr, unsigned data) {
  asm volatile("global_atomic_pk_add_f16 %0, %1, off" :: "v"(addr), "v"(data) : "memory");
}
__device__ __forceinline__ int hfind(const int* __restrict__ keys, int key) {
  unsigned i = ((unsigned)key * 2654435761u) >> 14 & HMASK;
  while (true) {
    int k = keys[i];
    if (k == key) return (int)i;
    if (k == -1) return -1;
    i = (i + 1) & HMASK;
  }
}
// bf16x2 helpers: low 16 bits = first (even-dim) element
__device__ __forceinline__ float2 bf2f(unsigned u) {
  return make_float2(__uint_as_float(u << 16), __uint_as_float(u & 0xffff0000u));
}
__device__ __forceinline__ unsigned f2bf(float a, float b) {
  unsigned ua = __float_as_uint(a);
  ua = (ua + 0x7fffu + ((ua >> 16) & 1u)) >> 16;
  unsigned ub = __float_as_uint(b);
  ub = ((ub + 0x7fffu + ((ub >> 16) & 1u)) >> 16) << 16;
  return (ua & 0xffffu) | ub;
}

// A: init + x->bf16 + per-block combo in LDS + node scalars. 512 blocks.
__global__ __launch_bounds__(256) void kA(const float* __restrict__ x,
                                          const float* __restrict__ embed,
                                          const float* __restrict__ gw,
                                          const float* __restrict__ att_s,
                                          const float* __restrict__ att_d,
                                          const float* __restrict__ lin_W,
                                          float4* __restrict__ pN, float4* __restrict__ qN,
                                          unsigned* __restrict__ xb,
                                          int* __restrict__ hKeys, unsigned* __restrict__ hPair,
                                          int* __restrict__ colCnt, float* __restrict__ gvec,
                                          unsigned* __restrict__ done, unsigned* __restrict__ gCur) {
  __shared__ float sm[768];  // cA | cD | cZ
  int t = threadIdx.x, bid = blockIdx.x;
  int lane = t & 63, wv = t >> 6;
  for (int i = bid * 256 + t; i < HSZ; i += 512 * 256) { hKeys[i] = -1; hPair[i] = 0u; }
  for (int i = bid * 256 + t; i < NN; i += 512 * 256) colCnt[i] = 0;
  if (bid == 0) {
    if (t < 128) gvec[t] = 0.f;
    if (t == 0) *done = 0u;
    for (int i = t; i < NBIN; i += 256) gCur[i] = 0u;  // FIX: NBIN=320 > 256
  }
  {  // x -> bf16 (8 elems/thread)
    const float4* x4 = (const float4*)x;
    float4 a = x4[bid * 512 + t * 2];
    float4 b = x4[bid * 512 + t * 2 + 1];
    uint4 o;
    o.x = f2bf(a.x, a.y); o.y = f2bf(a.z, a.w);
    o.z = f2bf(b.x, b.y); o.w = f2bf(b.z, b.w);
    ((uint4*)xb)[bid * 256 + t] = o;
  }
  {
    float sa = 0.f, sd = 0.f, sz = 0.f;
#pragma unroll 8
    for (int k = 0; k < 64; k++) {
      float w = gw[t * 64 + k];
      sa += w * att_s[k]; sd += w * att_d[k]; sz += w * lin_W[k];
    }
    sm[t] = sa; sm[256 + t] = sd; sm[512 + t] = sz;
  }
  __syncthreads();
#pragma unroll
  for (int j = 0; j < 4; j++) {
    int n = bid * 16 + wv * 4 + j;
    float e0 = embed[n * 128 + lane], e1 = embed[n * 128 + 64 + lane];
    float pA = wsum(e0 * sm[lane] + e1 * sm[64 + lane]);
    float qA = wsum(e0 * sm[128 + lane] + e1 * sm[192 + lane]);
    float pD = wsum(e0 * sm[256 + lane] + e1 * sm[320 + lane]);
    float qD = wsum(e0 * sm[384 + lane] + e1 * sm[448 + lane]);
    float pZ = wsum(e0 * sm[512 + lane] + e1 * sm[576 + lane]);
    float qZ = wsum(e0 * sm[640 + lane] + e1 * sm[704 + lane]);
    if (lane == 0) pN[n] = make_float4(pA, pD, pZ, 0.f);
    if (lane == 1) qN[n] = make_float4(qA, qD, qZ, 0.f);
  }
}

// B: per-edge scalars + col histogram
__global__ void kB(const int* __restrict__ row, const int* __restrict__ col,
                   const float4* __restrict__ pN, const float4* __restrict__ qN,
                   float2* __restrict__ asz, float* __restrict__ ad, int* __restrict__ colCnt) {
  int e = blockIdx.x * 256 + threadIdx.x;
  int r = row[e], c = col[e];
  float4 p = pN[r];
  float4 q = qN[c];
  asz[e] = make_float2(p.x + q.x, p.z + q.z);  // {a_s, z}
  ad[e] = p.y + q.y;
  atomicAdd(&colCnt[c], 1);
}

// C: blocks 0..319 partition edge2 into 320 dst bins (u32 payload (local<<17)|src);
//    block 320 runs the col-CSR scan concurrently (disjoint data).
__global__ __launch_bounds__(256) void kC(const int* __restrict__ src2, const int* __restrict__ dst2,
                                          const int* __restrict__ colCnt, int* __restrict__ colOffs,
                                          int* __restrict__ colCur,
                                          unsigned* __restrict__ gCur, unsigned* __restrict__ bucket) {
  int t = threadIdx.x;
  if (blockIdx.x == 320) {  // exclusive scan of colCnt (8192)
    __shared__ int sd32[256];
    int beg = t * 32;
    int s = 0;
#pragma unroll 8
    for (int i = 0; i < 32; i++) s += colCnt[beg + i];
    sd32[t] = s;
    __syncthreads();
    for (int o = 1; o < 256; o <<= 1) {
      int v = (t >= o) ? sd32[t - o] : 0;
      __syncthreads();
      sd32[t] += v;
      __syncthreads();
    }
    int run = (t == 0) ? 0 : sd32[t - 1];
    for (int i = 0; i < 32; i++) {
      colOffs[beg + i] = run;
      colCur[beg + i] = run;
      run += colCnt[beg + i];
    }
    if (t == 255) colOffs[NN] = run;
    return;
  }
  __shared__ unsigned hist[NBIN], base[NBIN], lcur[NBIN];
  for (int i = t; i < NBIN; i += 256) { hist[i] = 0u; lcur[i] = 0u; }
  __syncthreads();
  int blockBase = blockIdx.x * 4096;
  int4 dv[4];
#pragma unroll
  for (int j = 0; j < 4; j++) {
    dv[j] = *(const int4*)&dst2[blockBase + j * 1024 + t * 4];
    atomicAdd(&hist[dv[j].x >> 8], 1u);
    atomicAdd(&hist[dv[j].y >> 8], 1u);
    atomicAdd(&hist[dv[j].z >> 8], 1u);
    atomicAdd(&hist[dv[j].w >> 8], 1u);
  }
  __syncthreads();
  for (int i = t; i < NBIN; i += 256)
    if (hist[i]) base[i] = atomicAdd(&gCur[i], hist[i]);
  __syncthreads();
#pragma unroll
  for (int j = 0; j < 4; j++) {
    int4 sv = *(const int4*)&src2[blockBase + j * 1024 + t * 4];
    int ss[4] = {sv.x, sv.y, sv.z, sv.w};
    int dd[4] = {dv[j].x, dv[j].y, dv[j].z, dv[j].w};
#pragma unroll
    for (int k = 0; k < 4; k++) {
      int s = ss[k], d = dd[k];
      int b = d >> 8;
      unsigned r = atomicAdd(&lcur[b], 1u);
      unsigned pos = base[b] + r;
      if (pos < BCAP) bucket[(size_t)b * BCAP + pos] = ((unsigned)(d & 255) << SBITS) | (unsigned)s;
    }
  }
}

// D: per-bin reduce (4-wide ILP) + gate + hash insert (dn stays in LDS)
__global__ __launch_bounds__(256) void kD(const int* __restrict__ row, const int* __restrict__ col,
                                          const float2* __restrict__ asz, const float* __restrict__ ad,
                                          const unsigned* __restrict__ bucket, const unsigned* __restrict__ gCur,
                                          const float* __restrict__ gat_b, const float* __restrict__ lin_W,
                                          const float* __restrict__ lin_b, const float* __restrict__ noise,
                                          const float* __restrict__ tmp,
                                          int* __restrict__ hKeys, unsigned* __restrict__ hPair) {
  __shared__ float acc[512];  // 256 dsts x {denom, numer}
  __shared__ float adl[256];
  int b = blockIdx.x, t = threadIdx.x, lane = t & 63;
  acc[2 * t] = 0.f; acc[2 * t + 1] = 0.f; adl[t] = ad[b * 256 + t];
  __syncthreads();
  int cnt = min((int)gCur[b], BCAP);
  const unsigned* bp = bucket + (size_t)b * BCAP;
  const unsigned SM = (1u << SBITS) - 1;
  int i = t;
  for (; i + 768 < cnt; i += 1024) {
    unsigned u0 = bp[i], u1 = bp[i + 256], u2 = bp[i + 512], u3 = bp[i + 768];
    float2 az0 = asz[u0 & SM], az1 = asz[u1 & SM], az2 = asz[u2 & SM], az3 = asz[u3 & SM];
    int l0 = u0 >> SBITS, l1 = u1 >> SBITS, l2 = u2 >> SBITS, l3 = u3 >> SBITS;
    float ea0 = __expf(lrelu(az0.x + adl[l0]));
    float ea1 = __expf(lrelu(az1.x + adl[l1]));
    float ea2 = __expf(lrelu(az2.x + adl[l2]));
    float ea3 = __expf(lrelu(az3.x + adl[l3]));
    atomicAdd(&acc[2 * l0], ea0); atomicAdd(&acc[2 * l0 + 1], ea0 * az0.y);
    atomicAdd(&acc[2 * l1], ea1); atomicAdd(&acc[2 * l1 + 1], ea1 * az1.y);
    atomicAdd(&acc[2 * l2], ea2); atomicAdd(&acc[2 * l2 + 1], ea2 * az2.y);
    atomicAdd(&acc[2 * l3], ea3); atomicAdd(&acc[2 * l3 + 1], ea3 * az3.y);
  }
  for (; i < cnt; i += 256) {
    unsigned u = bp[i];
    float2 az = asz[u & SM];
    int l = u >> SBITS;
    float ea = __expf(lrelu(az.x + adl[l]));
    atomicAdd(&acc[2 * l], ea);
    atomicAdd(&acc[2 * l + 1], ea * az.y);
  }
  __syncthreads();
  float gb = wsum(gat_b[lane] * lin_W[lane]) + lin_b[0];
  float itmp = 1.f / tmp[0];
  {
    int e = b * 256 + t;
    float2 szv = asz[e];
    float eself = __expf(lrelu(szv.x + adl[t]));  // softmax shift-invariant
    float la = (acc[2 * t + 1] + eself * szv.y) / (acc[2 * t] + eself) + gb;
    float ns = noise[e];
    float g = (logf(ns) - log1pf(-ns) + la) * itmp;
    float gate = 1.f / (1.f + __expf(-g));
    int key = row[e] * NN + col[e];
    unsigned hi = ((unsigned)key * 2654435761u) >> 14 & HMASK;
    while (true) {
      int old = atomicCAS(&hKeys[hi], -1, key);
      if (old == -1 || old == key) break;
      hi = (hi + 1) & HMASK;
    }
    atomic_pk_add_f16(&hPair[hi], packh2(1.0f, gate));
  }
}

// E: edge_mask -> w; CSR scatter of packed (row, w)
__global__ void kE(const int* __restrict__ row, const int* __restrict__ col,
                   const int* __restrict__ hKeys, const unsigned* __restrict__ hPair,
                   int* __restrict__ colCur, int2* __restrict__ csrP) {
  int e = blockIdx.x * 256 + threadIdx.x;
  int r = row[e], c = col[e];
  int s1 = hfind(hKeys, r * NN + c);
  unsigned u1 = hPair[s1];
  __half2 h1 = *reinterpret_cast<__half2*>(&u1);
  float cv = __low2float(h1), g1 = __high2float(h1);
  int s2 = hfind(hKeys, c * NN + r);
  float g2 = 0.f;
  if (s2 >= 0) {
    unsigned u2 = hPair[s2];
    g2 = __high2float(*reinterpret_cast<__half2*>(&u2));
  }
  float em = cv * 0.5f * (g1 + g2);
  float w = 1.f / (1.f + __expf(-em));
  int pos = atomicAdd(&colCur[c], 1);
  csrP[pos] = make_int2(r, __float_as_int(w));
}

// gather one node's aggregated features (bf16 rows, 4-wide ILP); returns f32 pair
__device__ __forceinline__ float2 gatherNode(const unsigned* __restrict__ xb, int n, int lane,
                                             const int* __restrict__ colOffs,
                                             const int2* __restrict__ csrP) {
  float2 sf = bf2f(xb[n * 64 + lane]);
  float a0 = sf.x, a1 = sf.y, ws = 0.f;
  int off = colOffs[n], end = colOffs[n + 1];
  int i = off;
  for (; i + 4 <= end; i += 4) {
    int2 q0 = csrP[i], q1 = csrP[i + 1], q2 = csrP[i + 2], q3 = csrP[i + 3];
    unsigned u0 = xb[q0.x * 64 + lane];
    unsigned u1 = xb[q1.x * 64 + lane];
    unsigned u2 = xb[q2.x * 64 + lane];
    unsigned u3 = xb[q3.x * 64 + lane];
    float w0 = __int_as_float(q0.y), w1 = __int_as_float(q1.y);
    float w2 = __int_as_float(q2.y), w3 = __int_as_float(q3.y);
    ws += w0 + w1 + w2 + w3;
    float2 f0 = bf2f(u0), f1 = bf2f(u1), f2v = bf2f(u2), f3 = bf2f(u3);
    a0 += w0 * f0.x + w1 * f1.x + w2 * f2v.x + w3 * f3.x;
    a1 += w0 * f0.y + w1 * f1.y + w2 * f2v.y + w3 * f3.y;
  }
  for (; i < end; i++) {
    int2 q = csrP[i];
    unsigned u = xb[q.x * 64 + lane];
    float w = __int_as_float(q.y);
    ws += w;
    float2 f = bf2f(u);
    a0 += w * f.x;
    a1 += w * f.y;
  }
  float inv = 1.f / (1.f + ws);
  return make_float2(a0 * inv, a1 * inv);
}

// F: GCN layer. LDS = 32KB bf16 W + 8KB T = 40960B -> 4 blocks/CU.
__global__ __launch_bounds__(256) void kF(const unsigned* __restrict__ xb,
                                          const int* __restrict__ colOffs,
                                          const int2* __restrict__ csrP,
                                          const float* __restrict__ W,
                                          unsigned* __restrict__ outB) {
  __shared__ unsigned Wl[128 * 64];  // bf16x2
  __shared__ float Tl[16 * 128];
  int t = threadIdx.x;
  const float4* W4 = (const float4*)W;
  for (int i = t; i < 4096; i += 256) {
    float4 a = W4[i];
    ((uint2*)Wl)[i] = make_uint2(f2bf(a.x, a.y), f2bf(a.z, a.w));
  }
  int lane = t & 63, wv = t >> 6;
  int nb = blockIdx.x * 16;
#pragma unroll
  for (int j = 0; j < 4; j++) {
    int n = nb + wv * 4 + j;
    float2 tv = gatherNode(xb, n, lane, colOffs, csrP);
    ((float2*)Tl)[(wv * 4 + j) * 64 + lane] = tv;
  }
  __syncthreads();
  float2 acc[4];
#pragma unroll
  for (int j = 0; j < 4; j++) acc[j] = make_float2(0.f, 0.f);
  for (int k = 0; k < 128; k++) {
    float2 w2 = bf2f(Wl[k * 64 + lane]);
#pragma unroll
    for (int j = 0; j < 4; j++) {
      float tv = Tl[(wv * 4 + j) * 128 + k];  // broadcast read
      acc[j].x += tv * w2.x;
      acc[j].y += tv * w2.y;
    }
  }
#pragma unroll
  for (int j = 0; j < 4; j++) {
    int n = nb + wv * 4 + j;
    outB[n * 64 + lane] = f2bf(fmaxf(acc[j].x, 0.f), fmaxf(acc[j].y, 0.f));
  }
}

// H: layer3 + pool + final (done-counter; last block reads gvec via memory-side atomics)
__global__ __launch_bounds__(256) void kH(const unsigned* __restrict__ xb,
                                          const int* __restrict__ colOffs,
                                          const int2* __restrict__ csrP,
                                          const float* __restrict__ W,
                                          const float* __restrict__ Wc,
                                          float* __restrict__ gvec, unsigned* __restrict__ done,
                                          float* __restrict__ out) {
  __shared__ unsigned Wl[128 * 64];  // bf16x2
  __shared__ float Tl[16 * 128];     // reused for gpart + final scratch
  __shared__ unsigned lastFlag;
  int t = threadIdx.x;
  const float4* W4 = (const float4*)W;
  for (int i = t; i < 4096; i += 256) {
    float4 a = W4[i];
    ((uint2*)Wl)[i] = make_uint2(f2bf(a.x, a.y), f2bf(a.z, a.w));
  }
  int lane = t & 63, wv = t >> 6;
  int nb = blockIdx.x * 16;
#pragma unroll
  for (int j = 0; j < 4; j++) {
    int n = nb + wv * 4 + j;
    float2 tv = gatherNode(xb, n, lane, colOffs, csrP);
    ((float2*)Tl)[(wv * 4 + j) * 64 + lane] = tv;
  }
  __syncthreads();
  float2 acc[4];
#pragma unroll
  for (int j = 0; j < 4; j++) acc[j] = make_float2(0.f, 0.f);
  for (int k = 0; k < 128; k++) {
    float2 w2 = bf2f(Wl[k * 64 + lane]);
#pragma unroll
    for (int j = 0; j < 4; j++) {
      float tv = Tl[(wv * 4 + j) * 128 + k];
      acc[j].x += tv * w2.x;
      acc[j].y += tv * w2.y;
    }
  }
  // pool: H3 never written to memory
  float s0 = 0.f, s1 = 0.f;
#pragma unroll
  for (int j = 0; j < 4; j++) {
    s0 += fmaxf(acc[j].x, 0.f);
    s1 += fmaxf(acc[j].y, 0.f);
  }
  __syncthreads();  // all GEMM reads of Tl done; reuse as gpart
  float* gpart = Tl;
  if (t < 128) gpart[t] = 0.f;
  __syncthreads();
  atomicAdd(&gpart[2 * lane], s0);
  atomicAdd(&gpart[2 * lane + 1], s1);
  __syncthreads();
  if (t < 128) atomicAdd(&gvec[t], gpart[t]);
  __threadfence();
  __syncthreads();
  if (t == 0) lastFlag = (atomicAdd(done, 1u) == gridDim.x - 1) ? 1u : 0u;
  __syncthreads();
  if (lastFlag) {
    float* f0 = Tl + 256;
    float* f1 = Tl + 384;
    if (t < 128) {
      float gj = atomicAdd(&gvec[t], 0.f) * (1.0f / 8192.0f);  // memory-side read
      f0[t] = gj * Wc[t * 2 + 0];
      f1[t] = gj * Wc[t * 2 + 1];
    }
    __syncthreads();
    for (int o = 64; o > 0; o >>= 1) {
      if (t < o) { f0[t] += f0[t + o]; f1[t] += f1[t + o]; }
      __syncthreads();
    }
    if (t == 0) {
      float l0 = f0[0], l1 = f1[0];
      float m = fmaxf(l0, l1);
      float e0 = __expf(l0 - m), e1 = __expf(l1 - m);
      float inv = 1.f / (e0 + e1);
      out[0] = e0 * inv;
      out[1] = e1 * inv;
    }
  }
}

extern "C" void kernel_launch(void* const* d_in, const int* in_sizes, int n_in,
                              void* d_out, int out_size, void* d_ws, size_t ws_size,
                              hipStream_t stream) {
  const float* x     = (const float*)d_in[0];
  const float* embed = (const float*)d_in[1];
  const float* noise = (const float*)d_in[2];
  const float* tmp   = (const float*)d_in[3];
  const float* gat_W = (const float*)d_in[4];
  const float* att_s = (const float*)d_in[5];
  const float* att_d = (const float*)d_in[6];
  const float* gat_b = (const float*)d_in[7];
  const float* lin_W = (const float*)d_in[8];
  const float* lin_b = (const float*)d_in[9];
  const float* W1    = (const float*)d_in[10];
  const float* W2    = (const float*)d_in[11];
  const float* W3    = (const float*)d_in[12];
  const float* Wc    = (const float*)d_in[13];
  const int* ei      = (const int*)d_in[14];
  const int* nei     = (const int*)d_in[15];
  const int* row = ei;
  const int* col = ei + EE;
  const int* src2 = nei;
  const int* dst2 = nei + E2C;
  float* out = (float*)d_out;

  // workspace layout (4-byte units); 16B/8B-aligned buffers first
  char* w8 = (char*)d_ws;
  size_t off = 0;
  auto alloc = [&](size_t units) -> void* {
    void* p = w8 + off * 4;
    off += units;
    return p;
  };
  float4*   pN      = (float4*)alloc(4 * NN);
  float4*   qN      = (float4*)alloc(4 * NN);
  float2*   asz     = (float2*)alloc(2 * EE);
  int2*     csrP    = (int2*)alloc(2 * EE);
  unsigned* xb      = (unsigned*)alloc(NN * 64);
  unsigned* H1b     = (unsigned*)alloc(NN * 64);
  unsigned* H2b     = (unsigned*)alloc(NN * 64);
  float*    ad      = (float*)alloc(EE);
  int*      colCnt  = (int*)alloc(NN);
  int*      colOffs = (int*)alloc(NN + 2);
  int*      colCur  = (int*)alloc(NN);
  int*      hKeys   = (int*)alloc(HSZ);
  unsigned* hPair   = (unsigned*)alloc(HSZ);
  unsigned* bucket  = (unsigned*)alloc((size_t)NBIN * BCAP);
  unsigned* gCur    = (unsigned*)alloc(NBIN);
  float*    gvec    = (float*)alloc(128);
  unsigned* done    = (unsigned*)alloc(2);

  kA<<<512, 256, 0, stream>>>(x, embed, gat_W, att_s, att_d, lin_W, pN, qN, xb,
                              hKeys, hPair, colCnt, gvec, done, gCur);
  kB<<<EE / 256, 256, 0, stream>>>(row, col, pN, qN, asz, ad, colCnt);
  kC<<<321, 256, 0, stream>>>(src2, dst2, colCnt, colOffs, colCur, gCur, bucket);
  kD<<<NBIN, 256, 0, stream>>>(row, col, asz, ad, bucket, gCur, gat_b, lin_W,
                               lin_b, noise, tmp, hKeys, hPair);
  kE<<<EE / 256, 256, 0, stream>>>(row, col, hKeys, hPair, colCur, csrP);
  kF<<<NN / 16, 256, 0, stream>>>(xb, colOffs, csrP, W1, H1b);
  kF<<<NN / 16, 256, 0, stream>>>(H1b, colOffs, csrP, W2, H2b);
  kH<<<NN / 16, 256, 0, stream>>>(H2b, colOffs, csrP, W3, Wc, gvec, done, out);
}